// Round 9
// baseline (165.273 us; speedup 1.0000x reference)
//
#include <hip/hip_runtime.h>
#include <hip/hip_bf16.h>

// Problem constants
#define S_LEN   2048
#define BATCH   2
#define NH      16
#define DH      64
#define DMODEL  1024
#define MTOT    (BATCH * S_LEN)   // 4096

typedef __attribute__((ext_vector_type(4))) float f32x4;
typedef __attribute__((ext_vector_type(8))) short s16x8;   // 8 bf16
typedef __attribute__((ext_vector_type(4))) short s16x4;

#define MFMA_BF16(a, b, c) __builtin_amdgcn_mfma_f32_16x16x32_bf16((a), (b), (c), 0, 0, 0)

static __device__ __forceinline__ short f2bf(float f) {
    union { float f; unsigned u; } v; v.f = f;
    unsigned r = v.u + 0x7fffu + ((v.u >> 16) & 1u);
    return (short)(r >> 16);
}

static __device__ __forceinline__ unsigned cvtpk_bf16(float lo, float hi) {
    unsigned r;
    asm volatile("v_cvt_pk_bf16_f32 %0, %1, %2" : "=v"(r) : "v"(lo), "v"(hi));
    return r;
}

// async global->LDS, 16B per lane; dst is wave-uniform base (lane*16 added by HW)
static __device__ __forceinline__ void gload_lds16(const void* g, void* l) {
    __builtin_amdgcn_global_load_lds(
        (const __attribute__((address_space(1))) void*)g,
        (__attribute__((address_space(3))) void*)l, 16, 0, 0);
}

#define VM_WAIT(N) asm volatile("s_waitcnt vmcnt(" #N ")" ::: "memory")

// De-pinned barrier (m141): memory-only compile-time fences around s_barrier.
static __device__ __forceinline__ void barrier_sync() {
    asm volatile("" ::: "memory");
    __builtin_amdgcn_s_barrier();
    asm volatile("" ::: "memory");
}

// ---------------------------------------------------------------------------
// Prep 1: W[k][n] fp32 -> Wt[n][k] bf16 (transposed). grid (16,16,4).
// ---------------------------------------------------------------------------
__global__ __launch_bounds__(256) void prep_wt(const float* __restrict__ wq,
                                               const float* __restrict__ wk,
                                               const float* __restrict__ wv,
                                               const float* __restrict__ wo,
                                               short* __restrict__ wtb) {
    const float* W = (blockIdx.z == 0) ? wq : (blockIdx.z == 1) ? wk
                   : (blockIdx.z == 2) ? wv : wo;
    short* out = wtb + (size_t)blockIdx.z * DMODEL * DMODEL;

    __shared__ short T[64][72];
    const int t  = threadIdx.x;
    const int k0 = blockIdx.y * 64, n0 = blockIdx.x * 64;

    #pragma unroll
    for (int p = 0; p < 4; ++p) {
        const int kk = p * 16 + (t >> 4);
        const int nn = (t & 15) * 4;
        f32x4 v = *(const f32x4*)(W + (size_t)(k0 + kk) * DMODEL + n0 + nn);
        #pragma unroll
        for (int j = 0; j < 4; ++j) T[nn + j][kk] = f2bf(v[j]);
    }
    __syncthreads();
    #pragma unroll
    for (int p = 0; p < 4; ++p) {
        const int nn = p * 16 + (t >> 4);
        const int kk = (t & 15) * 4;
        *(s16x4*)(out + (size_t)(n0 + nn) * DMODEL + k0 + kk) = *(const s16x4*)&T[nn][kk];
    }
}

// ---------------------------------------------------------------------------
// Prep 2: x fp32 -> bf16
// ---------------------------------------------------------------------------
__global__ __launch_bounds__(256) void prep_x(const float* __restrict__ x,
                                              short* __restrict__ xb) {
    const size_t i = (size_t)(blockIdx.x * 256 + threadIdx.x) * 8;
    f32x4 a = *(const f32x4*)(x + i);
    f32x4 b = *(const f32x4*)(x + i + 4);
    s16x8 o;
    #pragma unroll
    for (int j = 0; j < 4; ++j) { o[j] = f2bf(a[j]); o[4 + j] = f2bf(b[j]); }
    *(s16x8*)(xb + i) = o;
}

// ---------------------------------------------------------------------------
// Prep 3: RoPE tables cos/sin [2048][32] fp32
// ---------------------------------------------------------------------------
__global__ __launch_bounds__(256) void prep_rope(float* __restrict__ cosT,
                                                 float* __restrict__ sinT) {
    const int idx = blockIdx.x * 256 + threadIdx.x;   // 65536 total
    const int s = idx >> 5, i = idx & 31;
    const float inv = exp2f(-(float)i * (13.287712379549449f / 32.0f));
    const float ang = (float)s * inv;
    cosT[idx] = cosf(ang);
    sinT[idx] = sinf(ang);
}

// ---------------------------------------------------------------------------
// FUSED QKV GEMM, 256x256 tile, BK=64, 8-phase schedule (m201 template).
// 512 threads = 8 waves (2M x 4N); per-wave C = 128x64 (acc[8][4]).
// Dynamic LDS 128KB: A[2buf][2half][128][64] at 0, B same at 32768 shorts.
// Per K-tile (BK=64): 4 phases of {ds_read subtile, stage calls, barrier,
// setprio+16 MFMA+setprio, barrier}; vmcnt(0) once per K-tile at phase 3.
// Chunk swizzle ^(row&7) both sides -> 2-way (free).
// grid 192 = 12tx x 16ty; XCD remap: each XCD owns 4ty x 6tx (A 2MB + B 3MB).
// ---------------------------------------------------------------------------
__global__ __launch_bounds__(512, 1) void gemm_qkv(const short* __restrict__ xb,
                                                   const short* __restrict__ wtb,
                                                   short* __restrict__ Qo,
                                                   short* __restrict__ Ko,
                                                   short* __restrict__ Vt,
                                                   const float* __restrict__ cosT,
                                                   const float* __restrict__ sinT) {
    extern __shared__ short SM[];                 // 65536 shorts = 128KB

    const int tid  = threadIdx.x;
    const int lane = tid & 63;
    const int wv   = tid >> 6;                    // 0..7
    const int wr   = wv >> 2;                     // 0..1 (M half)
    const int wc   = wv & 3;                      // 0..3 (N quarter)
    const int g = lane >> 4, c16 = lane & 15;

    // XCD remap: dd%8 = xcd; each XCD: 4 ty x 6 tx
    const int dd   = blockIdx.x + 12 * blockIdx.y;  // 0..191
    const int xcd  = dd & 7, local = dd >> 3;       // local 0..23
    const int ty   = (xcd & 3) * 4 + (local & 3);   // 0..15
    const int tx   = (xcd >> 2) * 6 + (local >> 2); // 0..11
    const int m0 = ty * 256, n0 = tx * 256;
    const int z  = tx >> 2;                       // 0:Q 1:K 2:V (uniform)

    // staging geometry: thread covers row (tid>>3) of a 64-row call region
    const int srow8 = tid >> 3;                   // 0..63
    const int schk  = (tid & 7) ^ (srow8 & 7);    // pre-swizzled global chunk
    const short* gA = xb  + (size_t)(m0 + srow8) * DMODEL + schk * 8;
    const short* gB = wtb + (size_t)(n0 + srow8) * DMODEL + schk * 8;
    const int lw = wv << 9;                       // wave-uniform LDS base

    // stage call: matrix mat (0=A,1=B), half h, sub c, K-tile kt, buf
    #define SC(mat, h, c, kt, buf) \
        gload_lds16((mat ? gB : gA) + (size_t)((h) * 128 + (c) * 64) * DMODEL + (size_t)(kt) * 64, \
                    SM + (mat) * 32768 + (buf) * 16384 + (h) * 8192 + (c) * 4096 + lw)

    // prologue: K-tile 0 -> buf 0 (8 calls)
    SC(0,0,0,0,0); SC(0,0,1,0,0); SC(0,1,0,0,0); SC(0,1,1,0,0);
    SC(1,0,0,0,0); SC(1,0,1,0,0); SC(1,1,0,0,0); SC(1,1,1,0,0);
    VM_WAIT(0);
    barrier_sync();

    f32x4 acc[8][4] = {};
    const int rx = c16 & 7;                       // read-swizzle key

    for (int kt = 0; kt < 16; ++kt) {
        const int cur  = kt & 1;
        const int nbuf = cur ^ 1;
        const short* Acur = SM + cur * 16384 + wr * 8192;
        const short* Bcur = SM + 32768 + cur * 16384 + (wc >> 1) * 8192 + (wc & 1) * 4096;
        const bool more = (kt < 15);

        s16x8 bfr[4][2];
        #pragma unroll
        for (int p = 0; p < 4; ++p) {
            // --- phase ds-reads ---
            if (p == 0) {
                #pragma unroll
                for (int j = 0; j < 4; ++j) {
                    const int brow = (j * 16 + c16) * 64;
                    bfr[j][0] = *(const s16x8*)&Bcur[brow + ((g ^ rx) << 3)];
                    bfr[j][1] = *(const s16x8*)&Bcur[brow + (((4 + g) ^ rx) << 3)];
                }
            }
            s16x8 af[2][2];
            #pragma unroll
            for (int ii = 0; ii < 2; ++ii) {
                const int arow = ((2 * p + ii) * 16 + c16) * 64;
                af[ii][0] = *(const s16x8*)&Acur[arow + ((g ^ rx) << 3)];
                af[ii][1] = *(const s16x8*)&Acur[arow + (((4 + g) ^ rx) << 3)];
            }
            // --- staged prefetch of K-tile kt+1 (3/3/2/0 split) ---
            if (more) {
                if (p == 0) { SC(0,0,0,kt+1,nbuf); SC(0,0,1,kt+1,nbuf); SC(0,1,0,kt+1,nbuf); }
                else if (p == 1) { SC(0,1,1,kt+1,nbuf); SC(1,0,0,kt+1,nbuf); SC(1,0,1,kt+1,nbuf); }
                else if (p == 2) { SC(1,1,0,kt+1,nbuf); SC(1,1,1,kt+1,nbuf); }
            }
            barrier_sync();
            __builtin_amdgcn_s_setprio(1);
            #pragma unroll
            for (int ii = 0; ii < 2; ++ii)
                #pragma unroll
                for (int j = 0; j < 4; ++j) {
                    acc[2 * p + ii][j] = MFMA_BF16(af[ii][0], bfr[j][0], acc[2 * p + ii][j]);
                    acc[2 * p + ii][j] = MFMA_BF16(af[ii][1], bfr[j][1], acc[2 * p + ii][j]);
                }
            __builtin_amdgcn_s_setprio(0);
            if (p == 3) { VM_WAIT(0); }
            barrier_sync();
        }
    }
    #undef SC

    // ------------------------- epilogue -------------------------
    const int hbase = (tx & 3) * 4;
    if (z < 2) {
        short* outp = (z == 0) ? Qo : Ko;
        const float post = (z == 0) ? 0.18033688011112042f : 1.0f;  // 0.125*log2(e)
        short (*RPq)[264] = (short(*)[264])SM;    // 128 x 264 shorts
        #pragma unroll 1
        for (int p2 = 0; p2 < 2; ++p2) {
            if (wr == p2) {
                #pragma unroll
                for (int j = 0; j < 4; ++j) {
                    const int nl = wc * 64 + j * 16 + c16;
                    const int d  = j * 16 + c16;
                    #pragma unroll
                    for (int i = 0; i < 8; ++i) {
                        #pragma unroll
                        for (int r = 0; r < 4; ++r) {
                            const int ml = i * 16 + g * 4 + r;
                            const int s  = (m0 + p2 * 128 + ml) & (S_LEN - 1);
                            float v = acc[i][j][r];
                            float vo = __shfl_xor(v, 1, 64);   // partner col n^1
                            float cs = cosT[s * 32 + (d >> 1)];
                            float sn = sinT[s * 32 + (d >> 1)];
                            float res = (d & 1) ? (vo * sn + v * cs) : (v * cs - vo * sn);
                            RPq[ml][nl] = f2bf(res * post);
                        }
                    }
                }
            }
            barrier_sync();
            #pragma unroll
            for (int ps = 0; ps < 8; ++ps) {
                const int idx = ps * 512 + tid;
                const int ss = idx >> 5, ch = idx & 31;
                const int m = m0 + p2 * 128 + ss;
                const int s = m & (S_LEN - 1), bb = m >> 11;
                short* dst = outp + (((size_t)bb * NH + hbase + (ch >> 3)) * S_LEN + s) * DH + (ch & 7) * 8;
                *(s16x8*)dst = *(const s16x8*)&RPq[ss][ch * 8];
            }
            barrier_sync();
        }
    } else {
        short (*RPv)[132] = (short(*)[132])SM;    // 256 x 132 shorts
        #pragma unroll 1
        for (int p2 = 0; p2 < 2; ++p2) {
            if (wr == p2) {
                #pragma unroll
                for (int j = 0; j < 4; ++j) {
                    const int nl = wc * 64 + j * 16 + c16;
                    #pragma unroll
                    for (int i = 0; i < 8; ++i) {
                        s16x4 pk;
                        #pragma unroll
                        for (int r = 0; r < 4; ++r) pk[r] = f2bf(acc[i][j][r]);
                        *(s16x4*)&RPv[nl][i * 16 + g * 4] = pk;
                    }
                }
            }
            barrier_sync();
            const int mb = m0 + p2 * 128;
            const int bb = mb >> 11, sr0 = mb & (S_LEN - 1);
            #pragma unroll
            for (int ps = 0; ps < 8; ++ps) {
                const int idx = ps * 512 + tid;
                const int row = idx >> 4, ch = idx & 15;
                const int h = hbase + (row >> 6), d = row & 63;
                short* dst = Vt + (((size_t)bb * NH + h) * DH + d) * S_LEN + sr0 + ch * 8;
                *(s16x8*)dst = *(const s16x8*)&RPv[row][ch * 8];
            }
            barrier_sync();
        }
    }
}

// ---------------------------------------------------------------------------
// 128x128 GEMM mainloop (R8 structure) for the output projection.
// ---------------------------------------------------------------------------
__device__ __forceinline__ void gemm_tile(const short* __restrict__ A,
                                          const short* __restrict__ Bt,
                                          int m0, int n0, short* SMl,
                                          f32x4 acc[4][4]) {
    const int tid  = threadIdx.x;
    const int lane = tid & 63;
    const int wv   = tid >> 6;
    const int wm   = (wv >> 1) * 64;
    const int wn   = (wv & 1) * 64;
    const int g = lane >> 4, c16 = lane & 15;

    short* Asb = SMl;
    short* Bsb = SMl + 12288;

    const int srow = tid >> 2;                          // 0..63
    const int schk = (tid & 3) ^ ((tid >> 3) & 3);      // chunk ^ (row>>1)&3
    const short* ga0 = A  + (size_t)(m0 + srow)      * DMODEL + schk * 8;
    const short* ga1 = A  + (size_t)(m0 + 64 + srow) * DMODEL + schk * 8;
    const short* gb0 = Bt + (size_t)(n0 + srow)      * DMODEL + schk * 8;
    const short* gb1 = Bt + (size_t)(n0 + 64 + srow) * DMODEL + schk * 8;
    const int lw = wv * 512;

    #define STAGE_G(buf, ko) do { \
        gload_lds16(ga0 + (ko), Asb + (buf) * 4096 + lw); \
        gload_lds16(ga1 + (ko), Asb + (buf) * 4096 + 2048 + lw); \
        gload_lds16(gb0 + (ko), Bsb + (buf) * 4096 + lw); \
        gload_lds16(gb1 + (ko), Bsb + (buf) * 4096 + 2048 + lw); \
    } while (0)

    STAGE_G(0, 0);
    STAGE_G(1, 32);

    const int rlo = (g ^ ((c16 >> 1) & 3)) << 3;
    for (int ks = 0; ks < 32; ++ks) {
        if (ks < 31) { VM_WAIT(4); } else { VM_WAIT(0); }
        barrier_sync();
        if (ks + 2 < 32) STAGE_G((ks + 2) % 3, (ks + 2) * 32);
        const int cur = ks % 3;
        s16x8 af[4], bfr[4];
        #pragma unroll
        for (int i = 0; i < 4; ++i)
            af[i] = *(const s16x8*)&Asb[cur * 4096 + (wm + i * 16 + c16) * 32 + rlo];
        #pragma unroll
        for (int j = 0; j < 4; ++j)
            bfr[j] = *(const s16x8*)&Bsb[cur * 4096 + (wn + j * 16 + c16) * 32 + rlo];
        #pragma unroll
        for (int i = 0; i < 4; ++i)
            #pragma unroll
            for (int j = 0; j < 4; ++j)
                acc[i][j] = MFMA_BF16(af[i], bfr[j], acc[i][j]);
    }
    #undef STAGE_G
}

// ---------------------------------------------------------------------------
// Causal flash attention (R6/R8 structure, unchanged).
// ---------------------------------------------------------------------------
__global__ __launch_bounds__(256) void attn(const short* __restrict__ Q,
                                            const short* __restrict__ K,
                                            const short* __restrict__ Vt,
                                            short* __restrict__ O) {
    const int tid  = threadIdx.x;
    const int lane = tid & 63;
    const int w    = tid >> 6;
    const int g = lane >> 4, c16 = lane & 15;
    const int bid  = blockIdx.x + 16 * blockIdx.y;  // 0..511
    const int cxcd = bid & 7, jj = bid >> 3;
    const int bh   = (jj & 3) * 8 + cxcd;           // 0..31
    const int bx   = jj >> 2;                       // 0..15
    const size_t base = (size_t)bh * S_LEN * DH;
    const short* Kb = K + base;
    const short* Vb = Vt + (size_t)bh * DH * S_LEN;
    const int b = bh >> 4, h = bh & 15;

    __shared__ __align__(16) short KL[3][4096];
    __shared__ __align__(16) short VL[3][4096];
    __shared__ __align__(16) short P2[4][16][72];

    const int kr = tid >> 3;
    const int kc = (tid & 7) ^ (kr & 7);
    const short* kg0 = Kb + (size_t)kr * DH + (kc << 3);
    const short* kg1 = Kb + (size_t)(32 + kr) * DH + (kc << 3);
    const short* vg0 = Vb + (size_t)kr * S_LEN + (kc << 3);
    const short* vg1 = Vb + (size_t)(32 + kr) * S_LEN + (kc << 3);
    const int lw = w * 512;
    const int kx = c16 & 7;

    #pragma unroll 1
    for (int half = 0; half < 2; ++half) {
        const int ci = half ? bx : 31 - bx;
        const int ntiles = ci + 1;
        const int wq0 = ci * 64 + w * 16;

        gload_lds16(kg0, &KL[0][lw]);
        gload_lds16(kg1, &KL[0][2048 + lw]);
        gload_lds16(vg0, &VL[0][lw]);
        gload_lds16(vg1, &VL[0][2048 + lw]);
        s16x8 bq0 = *(const s16x8*)(Q + base + (size_t)(wq0 + c16) * DH + g * 8);
        s16x8 bq1 = *(const s16x8*)(Q + base + (size_t)(wq0 + c16) * DH + 32 + g * 8);
        if (ntiles > 1) {
            gload_lds16(kg0 + (size_t)64 * DH, &KL[1][lw]);
            gload_lds16(kg1 + (size_t)64 * DH, &KL[1][2048 + lw]);
            gload_lds16(vg0 + 64, &VL[1][lw]);
            gload_lds16(vg1 + 64, &VL[1][2048 + lw]);
        }

        f32x4 o[4] = {};
        float lsum = 0.f;

        for (int tt = 0; tt < ntiles; ++tt) {
            if (tt + 1 < ntiles) { VM_WAIT(4); } else { VM_WAIT(0); }
            barrier_sync();
            if (tt + 2 < ntiles) {
                const int nb = (tt + 2) % 3;
                const size_t ko = (size_t)(tt + 2) * 64;
                gload_lds16(kg0 + ko * DH, &KL[nb][lw]);
                gload_lds16(kg1 + ko * DH, &KL[nb][2048 + lw]);
                gload_lds16(vg0 + ko,      &VL[nb][lw]);
                gload_lds16(vg1 + ko,      &VL[nb][2048 + lw]);
            }
            const int cur = tt % 3;

            f32x4 s[4];
            __builtin_amdgcn_s_setprio(1);
            #pragma unroll
            for (int cg = 0; cg < 4; ++cg) {
                const int krow = (cg * 16 + c16) * 64;
                s16x8 kf0 = *(const s16x8*)&KL[cur][krow + ((g ^ kx) << 3)];
                s16x8 kf1 = *(const s16x8*)&KL[cur][krow + (((4 + g) ^ kx) << 3)];
                f32x4 zz = {};
                zz = MFMA_BF16(kf0, bq0, zz);
                s[cg] = MFMA_BF16(kf1, bq1, zz);
            }
            __builtin_amdgcn_s_setprio(0);

            s16x8 vf[4][2];
            #pragma unroll
            for (int nt = 0; nt < 4; ++nt) {
                const int vr = (nt * 16 + c16) * 64;
                vf[nt][0] = *(const s16x8*)&VL[cur][vr + ((g ^ kx) << 3)];
                vf[nt][1] = *(const s16x8*)&VL[cur][vr + (((4 + g) ^ kx) << 3)];
            }

            const bool diag = (tt == ci);
            const int qrel = w * 16 + c16;
            #pragma unroll
            for (int cg = 0; cg < 4; ++cg) {
                float e[4];
                #pragma unroll
                for (int r = 0; r < 4; ++r) {
                    e[r] = exp2f(s[cg][r]);
                    if (diag && (cg * 16 + g * 4 + r > qrel)) e[r] = 0.f;
                }
                lsum += (e[0] + e[1]) + (e[2] + e[3]);
                uint2 pk;
                pk.x = cvtpk_bf16(e[0], e[1]);
                pk.y = cvtpk_bf16(e[2], e[3]);
                *(uint2*)&P2[w][c16][cg * 16 + g * 4] = pk;
            }
            asm volatile("s_waitcnt lgkmcnt(0)" ::: "memory");
            __builtin_amdgcn_sched_barrier(0);                // rule #18 fence
            s16x8 ap0 = *(const s16x8*)&P2[w][c16][g * 8];
            s16x8 ap1 = *(const s16x8*)&P2[w][c16][32 + g * 8];

            __builtin_amdgcn_s_setprio(1);
            #pragma unroll
            for (int nt = 0; nt < 4; ++nt) {
                o[nt] = MFMA_BF16(ap0, vf[nt][0], o[nt]);
                o[nt] = MFMA_BF16(ap1, vf[nt][1], o[nt]);
            }
            __builtin_amdgcn_s_setprio(0);
        }

        float lt = lsum;
        lt += __shfl_xor(lt, 16, 64);
        lt += __shfl_xor(lt, 32, 64);
        #pragma unroll
        for (int r = 0; r < 4; ++r) {
            const float linv = 1.0f / __shfl(lt, g * 4 + r, 64);
            #pragma unroll
            for (int nt = 0; nt < 4; ++nt) {
                O[((size_t)(b * S_LEN + wq0 + g * 4 + r)) * DMODEL
                  + h * DH + nt * 16 + c16] = f2bf(o[nt][r] * linv);
            }
        }
    }
}

// ---------------------------------------------------------------------------
// Output projection: C = Ob(bf16) @ wo, fp32 out. grid (8,32), XCD remap.
// ---------------------------------------------------------------------------
__global__ __launch_bounds__(256) void gemm_o(const short* __restrict__ Ob,
                                              const short* __restrict__ WoT,
                                              float* __restrict__ C) {
    __shared__ __align__(16) short SMl[24576];

    const int dd = blockIdx.x + 8 * blockIdx.y;   // xcd = dd%8
    const int ti = (dd & 7) * 32 + (dd >> 3);     // bijective (256 = 8*32)
    const int tx = ti & 7, ty = ti >> 3;
    const int m0 = ty * 128, n0 = tx * 128;

    f32x4 acc[4][4] = {};
    gemm_tile(Ob, WoT, m0, n0, SMl, acc);

    const int tid  = threadIdx.x;
    const int lane = tid & 63;
    const int wv   = tid >> 6;
    const int wm   = (wv >> 1) * 64, wn = (wv & 1) * 64;
    const int g = lane >> 4, c16 = lane & 15;

    #pragma unroll
    for (int i = 0; i < 4; ++i)
        #pragma unroll
        for (int j = 0; j < 4; ++j) {
            const int n = n0 + wn + j * 16 + c16;
            #pragma unroll
            for (int r = 0; r < 4; ++r) {
                const int m = m0 + wm + i * 16 + g * 4 + r;
                C[(size_t)m * DMODEL + n] = acc[i][j][r];
            }
        }
}

// ---------------------------------------------------------------------------
extern "C" void kernel_launch(void* const* d_in, const int* in_sizes, int n_in,
                              void* d_out, int out_size, void* d_ws, size_t ws_size,
                              hipStream_t stream) {
    const float* x  = (const float*)d_in[0];
    const float* wq = (const float*)d_in[1];
    const float* wk = (const float*)d_in[2];
    const float* wv = (const float*)d_in[3];
    const float* wo = (const float*)d_in[4];
    float* out = (float*)d_out;

    char* ws = (char*)d_ws;
    short* wtb  = (short*)ws;                              // [4][1024][1024] bf16 (q,k,v,o)
    short* xb   = (short*)(ws + (8ull  << 20));            // [4096][1024] bf16
    float* cosT = (float*)(ws + (16ull << 20));            // [2048][32]
    float* sinT = (float*)(ws + (16ull << 20) + (256ull << 10));
    short* Qb   = (short*)(ws + (17ull << 20));            // [B*H][S][64] bf16 (pre-scaled)
    short* Kb   = (short*)(ws + (25ull << 20));            // [B*H][S][64] bf16
    short* Vtb  = (short*)(ws + (33ull << 20));            // [B*H][64][S] bf16 (transposed)
    short* Ob   = (short*)(ws + (41ull << 20));            // [4096][1024] bf16

    prep_wt  <<<dim3(16, 16, 4), 256, 0, stream>>>(wq, wk, wv, wo, wtb);
    prep_x   <<<dim3(2048),      256, 0, stream>>>(x, xb);
    prep_rope<<<dim3(256),       256, 0, stream>>>(cosT, sinT);

    static bool attr_set = false;
    (void)hipFuncSetAttribute((const void*)gemm_qkv,
                              hipFuncAttributeMaxDynamicSharedMemorySize, 131072);
    (void)attr_set;

    gemm_qkv<<<dim3(12, 16), 512, 131072, stream>>>(xb, wtb, Qb, Kb, Vtb, cosT, sinT);
    attn    <<<dim3(16, 32), 256, 0, stream>>>(Qb, Kb, Vtb, Ob);
    gemm_o  <<<dim3(8, 32),  256, 0, stream>>>(Ob, wtb + 3ull * DMODEL * DMODEL, out);
}

// Round 10
// 110.021 us; speedup vs baseline: 1.5022x; 1.5022x over previous
//
#include <hip/hip_runtime.h>
#include <hip/hip_bf16.h>

// Problem constants
#define S_LEN   2048
#define BATCH   2
#define NH      16
#define DH      64
#define DMODEL  1024
#define MTOT    (BATCH * S_LEN)   // 4096

typedef __attribute__((ext_vector_type(4))) float f32x4;
typedef __attribute__((ext_vector_type(8))) short s16x8;   // 8 bf16
typedef __attribute__((ext_vector_type(4))) short s16x4;

#define MFMA_BF16(a, b, c) __builtin_amdgcn_mfma_f32_16x16x32_bf16((a), (b), (c), 0, 0, 0)

static __device__ __forceinline__ short f2bf(float f) {
    union { float f; unsigned u; } v; v.f = f;
    unsigned r = v.u + 0x7fffu + ((v.u >> 16) & 1u);
    return (short)(r >> 16);
}

static __device__ __forceinline__ unsigned cvtpk_bf16(float lo, float hi) {
    unsigned r;
    asm volatile("v_cvt_pk_bf16_f32 %0, %1, %2" : "=v"(r) : "v"(lo), "v"(hi));
    return r;
}

// async global->LDS, 16B per lane; dst is wave-uniform base (lane*16 added by HW)
static __device__ __forceinline__ void gload_lds16(const void* g, void* l) {
    __builtin_amdgcn_global_load_lds(
        (const __attribute__((address_space(1))) void*)g,
        (__attribute__((address_space(3))) void*)l, 16, 0, 0);
}

#define VM_WAIT(N) asm volatile("s_waitcnt vmcnt(" #N ")" ::: "memory")

// De-pinned barrier (m141 lesson): memory-only compile-time fences around a
// bare s_barrier. Orders LDS/global ops across the barrier for correctness
// but leaves MFMA/VALU/ds_read interleaving to the scheduler.
static __device__ __forceinline__ void barrier_sync() {
    asm volatile("" ::: "memory");
    __builtin_amdgcn_s_barrier();
    asm volatile("" ::: "memory");
}

// ---------------------------------------------------------------------------
// Fused prep. grid (16,16,5):
//   z<4 : W[k][n] fp32 -> Wt[n][k] bf16 (transposed), z selects wq/wk/wv/wo
//   z==4: x fp32 -> bf16 (8 chunks/thread) + RoPE cos/sin tables (1/thread)
// ---------------------------------------------------------------------------
__global__ __launch_bounds__(256) void prep_all(const float* __restrict__ wq,
                                                const float* __restrict__ wk,
                                                const float* __restrict__ wv,
                                                const float* __restrict__ wo,
                                                const float* __restrict__ x,
                                                short* __restrict__ wtb,
                                                short* __restrict__ xb,
                                                float* __restrict__ cosT,
                                                float* __restrict__ sinT) {
    const int t = threadIdx.x;
    if (blockIdx.z < 4) {
        const float* W = (blockIdx.z == 0) ? wq : (blockIdx.z == 1) ? wk
                       : (blockIdx.z == 2) ? wv : wo;
        short* out = wtb + (size_t)blockIdx.z * DMODEL * DMODEL;

        __shared__ short T[64][72];
        const int k0 = blockIdx.y * 64, n0 = blockIdx.x * 64;

        #pragma unroll
        for (int p = 0; p < 4; ++p) {
            const int kk = p * 16 + (t >> 4);
            const int nn = (t & 15) * 4;
            f32x4 v = *(const f32x4*)(W + (size_t)(k0 + kk) * DMODEL + n0 + nn);
            #pragma unroll
            for (int j = 0; j < 4; ++j) T[nn + j][kk] = f2bf(v[j]);
        }
        __syncthreads();
        #pragma unroll
        for (int p = 0; p < 4; ++p) {
            const int nn = p * 16 + (t >> 4);
            const int kk = (t & 15) * 4;
            *(s16x4*)(out + (size_t)(n0 + nn) * DMODEL + k0 + kk) = *(const s16x4*)&T[nn][kk];
        }
    } else {
        const int blk = blockIdx.y * 16 + blockIdx.x;   // 0..255
        // x convert: 8 chunks of 8 bf16 per thread
        #pragma unroll
        for (int jj = 0; jj < 8; ++jj) {
            const size_t i = ((size_t)jj * 65536 + blk * 256 + t) * 8;
            f32x4 a = *(const f32x4*)(x + i);
            f32x4 b = *(const f32x4*)(x + i + 4);
            s16x8 o;
            #pragma unroll
            for (int j = 0; j < 4; ++j) { o[j] = f2bf(a[j]); o[4 + j] = f2bf(b[j]); }
            *(s16x8*)(xb + i) = o;
        }
        // RoPE tables: one element per thread (65536 total)
        const int idx = blk * 256 + t;
        const int s = idx >> 5, ii = idx & 31;
        const float inv = exp2f(-(float)ii * (13.287712379549449f / 32.0f));
        const float ang = (float)s * inv;
        cosT[idx] = cosf(ang);
        sinT[idx] = sinf(ang);
    }
}

// ---------------------------------------------------------------------------
// 128x128 GEMM mainloop, BK=32, triple-buffered global_load_lds staging,
// issue-ahead-2, counted vmcnt(4). SM = 24576 shorts (48KB):
// As = SM[0..12287] (3 bufs x 4096), Bs = SM[12288..].
// LDS swizzle: chunk ^= (row>>1)&3 both sides -> 2-way (free).
// ---------------------------------------------------------------------------
__device__ __forceinline__ void gemm_tile(const short* __restrict__ A,
                                          const short* __restrict__ Bt,
                                          int m0, int n0, short* SM,
                                          f32x4 acc[4][4]) {
    const int tid  = threadIdx.x;
    const int lane = tid & 63;
    const int wv   = tid >> 6;
    const int wm   = (wv >> 1) * 64;
    const int wn   = (wv & 1) * 64;
    const int g = lane >> 4, c16 = lane & 15;

    short* Asb = SM;
    short* Bsb = SM + 12288;

    const int srow = tid >> 2;                          // 0..63
    const int schk = (tid & 3) ^ ((tid >> 3) & 3);      // chunk ^ (row>>1)&3
    const short* ga0 = A  + (size_t)(m0 + srow)      * DMODEL + schk * 8;
    const short* ga1 = A  + (size_t)(m0 + 64 + srow) * DMODEL + schk * 8;
    const short* gb0 = Bt + (size_t)(n0 + srow)      * DMODEL + schk * 8;
    const short* gb1 = Bt + (size_t)(n0 + 64 + srow) * DMODEL + schk * 8;
    const int lw = wv * 512;                      // wave-uniform LDS base (shorts)

    #define STAGE_G(buf, ko) do { \
        gload_lds16(ga0 + (ko), Asb + (buf) * 4096 + lw); \
        gload_lds16(ga1 + (ko), Asb + (buf) * 4096 + 2048 + lw); \
        gload_lds16(gb0 + (ko), Bsb + (buf) * 4096 + lw); \
        gload_lds16(gb1 + (ko), Bsb + (buf) * 4096 + 2048 + lw); \
    } while (0)

    STAGE_G(0, 0);
    STAGE_G(1, 32);

    const int rlo = (g ^ ((c16 >> 1) & 3)) << 3;  // read chunk (swizzled)
    for (int ks = 0; ks < 32; ++ks) {
        if (ks < 31) { VM_WAIT(4); } else { VM_WAIT(0); }
        barrier_sync();
        if (ks + 2 < 32) STAGE_G((ks + 2) % 3, (ks + 2) * 32);
        const int cur = ks % 3;
        s16x8 af[4], bfr[4];
        #pragma unroll
        for (int i = 0; i < 4; ++i)
            af[i] = *(const s16x8*)&Asb[cur * 4096 + (wm + i * 16 + c16) * 32 + rlo];
        #pragma unroll
        for (int j = 0; j < 4; ++j)
            bfr[j] = *(const s16x8*)&Bsb[cur * 4096 + (wn + j * 16 + c16) * 32 + rlo];
        #pragma unroll
        for (int i = 0; i < 4; ++i)
            #pragma unroll
            for (int j = 0; j < 4; ++j)
                acc[i][j] = MFMA_BF16(af[i], bfr[j], acc[i][j]);
    }
    #undef STAGE_G
}

// ---------------------------------------------------------------------------
// FUSED QKV GEMM (N=3072) + RoPE epilogue with LDS-repacked COALESCED stores.
// grid (24,32) = 768 blocks = 3/CU. Balanced XCD remap: each XCD owns
// 12 tx x 8 ty (B-panel 3MB + A-panel 2MB per XCD L2 vs 6MB B-restream).
// Epilogue: acc -> LDS tile (stride 136 shorts) -> 16B coalesced stores.
// ---------------------------------------------------------------------------
__global__ __launch_bounds__(256) void gemm_qkv(const short* __restrict__ xb,
                                                const short* __restrict__ wtb,
                                                short* __restrict__ Qo,
                                                short* __restrict__ Ko,
                                                short* __restrict__ Vt,
                                                const float* __restrict__ cosT,
                                                const float* __restrict__ sinT) {
    __shared__ __align__(16) short SM[24576];     // 48KB: staging, then repack

    const int dd    = blockIdx.x + 24 * blockIdx.y;  // dispatch index, xcd = dd%8
    const int xcd   = dd & 7;
    const int local = dd >> 3;                       // 0..95
    const int ty = (xcd & 3) * 8 + local / 12;       // 0..31
    const int tx = (xcd >> 2) * 12 + local % 12;     // 0..23
    const int m0 = ty * 128, n0 = tx * 128;
    const int z  = tx >> 3;                       // 0:Q 1:K 2:V (uniform/block)

    f32x4 acc[4][4] = {};
    gemm_tile(xb, wtb, m0, n0, SM, acc);

    const int tid  = threadIdx.x;
    const int lane = tid & 63;
    const int wv   = tid >> 6;
    const int wm   = (wv >> 1) * 64, wn = (wv & 1) * 64;
    const int g = lane >> 4, c16 = lane & 15;
    const int hbase = (n0 & 1023) >> 6;

    barrier_sync();                               // staging reads done -> reuse SM
    short (*RP)[136] = (short(*)[136])SM;         // 128 x 136 shorts (34.8KB)

    if (z < 2) {
        short* outp = (z == 0) ? Qo : Ko;
        const float post = (z == 0) ? 0.18033688011112042f : 1.0f;  // 0.125*log2(e)
        // write phase: RoPE + RP[m_local][n_local]
        #pragma unroll
        for (int j = 0; j < 4; ++j) {
            const int nl = wn + j * 16 + c16;
            const int d  = (n0 + nl) & 63;
            #pragma unroll
            for (int i = 0; i < 4; ++i) {
                #pragma unroll
                for (int r = 0; r < 4; ++r) {
                    const int ml = wm + i * 16 + g * 4 + r;
                    const int s  = (m0 + ml) & (S_LEN - 1);
                    float v = acc[i][j][r];
                    float vo = __shfl_xor(v, 1, 64);   // partner col = n^1
                    float cs = cosT[s * 32 + (d >> 1)];
                    float sn = sinT[s * 32 + (d >> 1)];
                    float res = (d & 1) ? (vo * sn + v * cs) : (v * cs - vo * sn);
                    RP[ml][nl] = f2bf(res * post);
                }
            }
        }
        barrier_sync();
        // store phase: row = (hh,ss), 8 lanes x 16B per 128B row
        #pragma unroll
        for (int pass = 0; pass < 8; ++pass) {
            const int row = pass * 32 + (tid >> 3);   // 0..255
            const int k   = tid & 7;
            const int hh = row >> 7, ss = row & 127;
            const int m = m0 + ss;
            const int s = m & (S_LEN - 1), b = m >> 11;
            short* dst = outp + (((size_t)b * NH + hbase + hh) * S_LEN + s) * DH + k * 8;
            *(s16x8*)dst = *(const s16x8*)&RP[ss][hh * 64 + k * 8];
        }
    } else {
        // V: RP[n_local][m_local] (transposed), then coalesced rows along sr
        #pragma unroll
        for (int j = 0; j < 4; ++j) {
            const int nl = wn + j * 16 + c16;
            #pragma unroll
            for (int i = 0; i < 4; ++i) {
                const int mlb = wm + i * 16 + g * 4;
                s16x4 pk;
                #pragma unroll
                for (int r = 0; r < 4; ++r) pk[r] = f2bf(acc[i][j][r]);
                *(s16x4*)&RP[nl][mlb] = pk;
            }
        }
        barrier_sync();
        const int b = m0 >> 11, sr0 = m0 & (S_LEN - 1);
        #pragma unroll
        for (int pass = 0; pass < 8; ++pass) {
            const int row = pass * 16 + (tid >> 4);   // 0..127 (h,d rows)
            const int k   = tid & 15;
            const int h = hbase + (row >> 6), d = row & 63;
            short* dst = Vt + (((size_t)b * NH + h) * DH + d) * S_LEN + sr0 + k * 8;
            *(s16x8*)dst = *(const s16x8*)&RP[row][k * 8];
        }
    }
}

// ---------------------------------------------------------------------------
// Causal flash attention, BALANCED merged blocks + swapped QK^T (R6 struct,
// de-pinned barriers). 512 blocks, 33 tiles each, lane-local softmax.
// ---------------------------------------------------------------------------
__global__ __launch_bounds__(256) void attn(const short* __restrict__ Q,
                                            const short* __restrict__ K,
                                            const short* __restrict__ Vt,
                                            short* __restrict__ O) {
    const int tid  = threadIdx.x;
    const int lane = tid & 63;
    const int w    = tid >> 6;
    const int g = lane >> 4, c16 = lane & 15;
    const int bid  = blockIdx.x + 16 * blockIdx.y;  // 0..511
    const int cxcd = bid & 7, jj = bid >> 3;
    const int bh   = (jj & 3) * 8 + cxcd;           // 0..31
    const int bx   = jj >> 2;                       // 0..15
    const size_t base = (size_t)bh * S_LEN * DH;
    const short* Kb = K + base;
    const short* Vb = Vt + (size_t)bh * DH * S_LEN;
    const int b = bh >> 4, h = bh & 15;

    __shared__ __align__(16) short KL[3][4096];   // [64 kv][64 d] swizzled chunks
    __shared__ __align__(16) short VL[3][4096];   // [64 d][64 kv] swizzled chunks
    __shared__ __align__(16) short P2[4][16][72]; // per-wave P^T[q][kv]

    const int kr = tid >> 3;                      // 0..31
    const int kc = (tid & 7) ^ (kr & 7);
    const short* kg0 = Kb + (size_t)kr * DH + (kc << 3);
    const short* kg1 = Kb + (size_t)(32 + kr) * DH + (kc << 3);
    const short* vg0 = Vb + (size_t)kr * S_LEN + (kc << 3);
    const short* vg1 = Vb + (size_t)(32 + kr) * S_LEN + (kc << 3);
    const int lw = w * 512;                       // wave-uniform LDS base (shorts)
    const int kx = c16 & 7;

    #pragma unroll 1
    for (int half = 0; half < 2; ++half) {
        const int ci = half ? bx : 31 - bx;       // big chunk first
        const int ntiles = ci + 1;
        const int wq0 = ci * 64 + w * 16;

        gload_lds16(kg0, &KL[0][lw]);
        gload_lds16(kg1, &KL[0][2048 + lw]);
        gload_lds16(vg0, &VL[0][lw]);
        gload_lds16(vg1, &VL[0][2048 + lw]);
        s16x8 bq0 = *(const s16x8*)(Q + base + (size_t)(wq0 + c16) * DH + g * 8);
        s16x8 bq1 = *(const s16x8*)(Q + base + (size_t)(wq0 + c16) * DH + 32 + g * 8);
        if (ntiles > 1) {
            gload_lds16(kg0 + (size_t)64 * DH, &KL[1][lw]);
            gload_lds16(kg1 + (size_t)64 * DH, &KL[1][2048 + lw]);
            gload_lds16(vg0 + 64, &VL[1][lw]);
            gload_lds16(vg1 + 64, &VL[1][2048 + lw]);
        }

        f32x4 o[4] = {};
        float lsum = 0.f;

        for (int tt = 0; tt < ntiles; ++tt) {
            if (tt + 1 < ntiles) { VM_WAIT(4); } else { VM_WAIT(0); }
            barrier_sync();
            if (tt + 2 < ntiles) {
                const int nb = (tt + 2) % 3;
                const size_t ko = (size_t)(tt + 2) * 64;
                gload_lds16(kg0 + ko * DH, &KL[nb][lw]);
                gload_lds16(kg1 + ko * DH, &KL[nb][2048 + lw]);
                gload_lds16(vg0 + ko,      &VL[nb][lw]);
                gload_lds16(vg1 + ko,      &VL[nb][2048 + lw]);
            }
            const int cur = tt % 3;

            // QK^T swapped: A=K rows (kv), B=Q -> s[cg] = S^T[kv][q=c16]
            f32x4 s[4];
            __builtin_amdgcn_s_setprio(1);
            #pragma unroll
            for (int cg = 0; cg < 4; ++cg) {
                const int krow = (cg * 16 + c16) * 64;
                s16x8 kf0 = *(const s16x8*)&KL[cur][krow + ((g ^ kx) << 3)];
                s16x8 kf1 = *(const s16x8*)&KL[cur][krow + (((4 + g) ^ kx) << 3)];
                f32x4 zz = {};
                zz = MFMA_BF16(kf0, bq0, zz);
                s[cg] = MFMA_BF16(kf1, bq1, zz);
            }
            __builtin_amdgcn_s_setprio(0);

            s16x8 vf[4][2];
            #pragma unroll
            for (int nt = 0; nt < 4; ++nt) {
                const int vr = (nt * 16 + c16) * 64;
                vf[nt][0] = *(const s16x8*)&VL[cur][vr + ((g ^ kx) << 3)];
                vf[nt][1] = *(const s16x8*)&VL[cur][vr + (((4 + g) ^ kx) << 3)];
            }

            const bool diag = (tt == ci);
            const int qrel = w * 16 + c16;
            #pragma unroll
            for (int cg = 0; cg < 4; ++cg) {
                float e[4];
                #pragma unroll
                for (int r = 0; r < 4; ++r) {
                    e[r] = exp2f(s[cg][r]);
                    if (diag && (cg * 16 + g * 4 + r > qrel)) e[r] = 0.f;
                }
                lsum += (e[0] + e[1]) + (e[2] + e[3]);
                uint2 pk;
                pk.x = cvtpk_bf16(e[0], e[1]);
                pk.y = cvtpk_bf16(e[2], e[3]);
                *(uint2*)&P2[w][c16][cg * 16 + g * 4] = pk;   // ds_write_b64
            }
            asm volatile("s_waitcnt lgkmcnt(0)" ::: "memory");
            __builtin_amdgcn_sched_barrier(0);                // rule #18 fence
            s16x8 ap0 = *(const s16x8*)&P2[w][c16][g * 8];    // ds_read_b128
            s16x8 ap1 = *(const s16x8*)&P2[w][c16][32 + g * 8];

            __builtin_amdgcn_s_setprio(1);
            #pragma unroll
            for (int nt = 0; nt < 4; ++nt) {
                o[nt] = MFMA_BF16(ap0, vf[nt][0], o[nt]);
                o[nt] = MFMA_BF16(ap1, vf[nt][1], o[nt]);
            }
            __builtin_amdgcn_s_setprio(0);
        }

        float lt = lsum;
        lt += __shfl_xor(lt, 16, 64);
        lt += __shfl_xor(lt, 32, 64);
        #pragma unroll
        for (int r = 0; r < 4; ++r) {
            const float linv = 1.0f / __shfl(lt, g * 4 + r, 64);
            #pragma unroll
            for (int nt = 0; nt < 4; ++nt) {
                O[((size_t)(b * S_LEN + wq0 + g * 4 + r)) * DMODEL
                  + h * DH + nt * 16 + c16] = f2bf(o[nt][r] * linv);
            }
        }
    }
}

// ---------------------------------------------------------------------------
// Output projection: C = Ob(bf16) @ wo, fp32 out. grid (8,32), XCD remap
// (per XCD: all 8 tx x 4 ty -> B 2MB + A 1MB, L2-resident).
// ---------------------------------------------------------------------------
__global__ __launch_bounds__(256) void gemm_o(const short* __restrict__ Ob,
                                              const short* __restrict__ WoT,
                                              float* __restrict__ C) {
    __shared__ __align__(16) short SMl[24576];

    const int dd = blockIdx.x + 8 * blockIdx.y;   // xcd = dd%8
    const int ti = (dd & 7) * 32 + (dd >> 3);     // bijective (256 = 8*32)
    const int tx = ti & 7, ty = ti >> 3;
    const int m0 = ty * 128, n0 = tx * 128;

    f32x4 acc[4][4] = {};
    gemm_tile(Ob, WoT, m0, n0, SMl, acc);

    const int tid  = threadIdx.x;
    const int lane = tid & 63;
    const int wv   = tid >> 6;
    const int wm   = (wv >> 1) * 64, wn = (wv & 1) * 64;
    const int g = lane >> 4, c16 = lane & 15;

    #pragma unroll
    for (int i = 0; i < 4; ++i)
        #pragma unroll
        for (int j = 0; j < 4; ++j) {
            const int n = n0 + wn + j * 16 + c16;
            #pragma unroll
            for (int r = 0; r < 4; ++r) {
                const int m = m0 + wm + i * 16 + g * 4 + r;
                C[(size_t)m * DMODEL + n] = acc[i][j][r];
            }
        }
}

// ---------------------------------------------------------------------------
extern "C" void kernel_launch(void* const* d_in, const int* in_sizes, int n_in,
                              void* d_out, int out_size, void* d_ws, size_t ws_size,
                              hipStream_t stream) {
    const float* x  = (const float*)d_in[0];
    const float* wq = (const float*)d_in[1];
    const float* wk = (const float*)d_in[2];
    const float* wv = (const float*)d_in[3];
    const float* wo = (const float*)d_in[4];
    float* out = (float*)d_out;

    char* ws = (char*)d_ws;
    short* wtb  = (short*)ws;                              // [4][1024][1024] bf16 (q,k,v,o)
    short* xb   = (short*)(ws + (8ull  << 20));            // [4096][1024] bf16
    float* cosT = (float*)(ws + (16ull << 20));            // [2048][32]
    float* sinT = (float*)(ws + (16ull << 20) + (256ull << 10));
    short* Qb   = (short*)(ws + (17ull << 20));            // [B*H][S][64] bf16 (pre-scaled)
    short* Kb   = (short*)(ws + (25ull << 20));            // [B*H][S][64] bf16
    short* Vtb  = (short*)(ws + (33ull << 20));            // [B*H][64][S] bf16 (transposed)
    short* Ob   = (short*)(ws + (41ull << 20));            // [4096][1024] bf16

    prep_all<<<dim3(16, 16, 5), 256, 0, stream>>>(wq, wk, wv, wo, x,
                                                  wtb, xb, cosT, sinT);

    gemm_qkv<<<dim3(24, 32), 256, 0, stream>>>(xb, wtb, Qb, Kb, Vtb, cosT, sinT);
    attn    <<<dim3(16, 32), 256, 0, stream>>>(Qb, Kb, Vtb, Ob);
    gemm_o  <<<dim3(8, 32),  256, 0, stream>>>(Ob, wtb + 3ull * DMODEL * DMODEL, out);
}

// Round 11
// 109.237 us; speedup vs baseline: 1.5130x; 1.0072x over previous
//
#include <hip/hip_runtime.h>
#include <hip/hip_bf16.h>

// Problem constants
#define S_LEN   2048
#define BATCH   2
#define NH      16
#define DH      64
#define DMODEL  1024
#define MTOT    (BATCH * S_LEN)   // 4096

typedef __attribute__((ext_vector_type(4))) float f32x4;
typedef __attribute__((ext_vector_type(8))) short s16x8;   // 8 bf16
typedef __attribute__((ext_vector_type(4))) short s16x4;

#define MFMA_BF16(a, b, c) __builtin_amdgcn_mfma_f32_16x16x32_bf16((a), (b), (c), 0, 0, 0)

static __device__ __forceinline__ short f2bf(float f) {
    union { float f; unsigned u; } v; v.f = f;
    unsigned r = v.u + 0x7fffu + ((v.u >> 16) & 1u);
    return (short)(r >> 16);
}

static __device__ __forceinline__ unsigned cvtpk_bf16(float lo, float hi) {
    unsigned r;
    asm volatile("v_cvt_pk_bf16_f32 %0, %1, %2" : "=v"(r) : "v"(lo), "v"(hi));
    return r;
}

// async global->LDS, 16B per lane; dst is wave-uniform base (lane*16 added by HW)
static __device__ __forceinline__ void gload_lds16(const void* g, void* l) {
    __builtin_amdgcn_global_load_lds(
        (const __attribute__((address_space(1))) void*)g,
        (__attribute__((address_space(3))) void*)l, 16, 0, 0);
}

#define VM_WAIT(N) asm volatile("s_waitcnt vmcnt(" #N ")" ::: "memory")

// De-pinned barrier (m141 lesson): memory-only compile-time fences around a
// bare s_barrier.
static __device__ __forceinline__ void barrier_sync() {
    asm volatile("" ::: "memory");
    __builtin_amdgcn_s_barrier();
    asm volatile("" ::: "memory");
}

// ---------------------------------------------------------------------------
// Fused prep. grid (16,16,5):
//   z<4 : W[k][n] fp32 -> Wt[n][k] bf16 (transposed), z selects wq/wk/wv/wo
//   z==4: x fp32 -> bf16 (8 chunks/thread) + RoPE cos/sin tables (1/thread)
// ---------------------------------------------------------------------------
__global__ __launch_bounds__(256) void prep_all(const float* __restrict__ wq,
                                                const float* __restrict__ wk,
                                                const float* __restrict__ wv,
                                                const float* __restrict__ wo,
                                                const float* __restrict__ x,
                                                short* __restrict__ wtb,
                                                short* __restrict__ xb,
                                                float* __restrict__ cosT,
                                                float* __restrict__ sinT) {
    const int t = threadIdx.x;
    if (blockIdx.z < 4) {
        const float* W = (blockIdx.z == 0) ? wq : (blockIdx.z == 1) ? wk
                       : (blockIdx.z == 2) ? wv : wo;
        short* out = wtb + (size_t)blockIdx.z * DMODEL * DMODEL;

        __shared__ short T[64][72];
        const int k0 = blockIdx.y * 64, n0 = blockIdx.x * 64;

        #pragma unroll
        for (int p = 0; p < 4; ++p) {
            const int kk = p * 16 + (t >> 4);
            const int nn = (t & 15) * 4;
            f32x4 v = *(const f32x4*)(W + (size_t)(k0 + kk) * DMODEL + n0 + nn);
            #pragma unroll
            for (int j = 0; j < 4; ++j) T[nn + j][kk] = f2bf(v[j]);
        }
        __syncthreads();
        #pragma unroll
        for (int p = 0; p < 4; ++p) {
            const int nn = p * 16 + (t >> 4);
            const int kk = (t & 15) * 4;
            *(s16x4*)(out + (size_t)(n0 + nn) * DMODEL + k0 + kk) = *(const s16x4*)&T[nn][kk];
        }
    } else {
        const int blk = blockIdx.y * 16 + blockIdx.x;   // 0..255
        #pragma unroll
        for (int jj = 0; jj < 8; ++jj) {
            const size_t i = ((size_t)jj * 65536 + blk * 256 + t) * 8;
            f32x4 a = *(const f32x4*)(x + i);
            f32x4 b = *(const f32x4*)(x + i + 4);
            s16x8 o;
            #pragma unroll
            for (int j = 0; j < 4; ++j) { o[j] = f2bf(a[j]); o[4 + j] = f2bf(b[j]); }
            *(s16x8*)(xb + i) = o;
        }
        const int idx = blk * 256 + t;
        const int s = idx >> 5, ii = idx & 31;
        const float inv = exp2f(-(float)ii * (13.287712379549449f / 32.0f));
        const float ang = (float)s * inv;
        cosT[idx] = cosf(ang);
        sinT[idx] = sinf(ang);
    }
}

// ---------------------------------------------------------------------------
// 128x128 GEMM mainloop, BK=32, triple-buffered global_load_lds staging,
// issue-ahead-2, counted vmcnt(4). SM = 24576 shorts (48KB).
// ---------------------------------------------------------------------------
__device__ __forceinline__ void gemm_tile(const short* __restrict__ A,
                                          const short* __restrict__ Bt,
                                          int m0, int n0, short* SM,
                                          f32x4 acc[4][4]) {
    const int tid  = threadIdx.x;
    const int lane = tid & 63;
    const int wv   = tid >> 6;
    const int wm   = (wv >> 1) * 64;
    const int wn   = (wv & 1) * 64;
    const int g = lane >> 4, c16 = lane & 15;

    short* Asb = SM;
    short* Bsb = SM + 12288;

    const int srow = tid >> 2;                          // 0..63
    const int schk = (tid & 3) ^ ((tid >> 3) & 3);      // chunk ^ (row>>1)&3
    const short* ga0 = A  + (size_t)(m0 + srow)      * DMODEL + schk * 8;
    const short* ga1 = A  + (size_t)(m0 + 64 + srow) * DMODEL + schk * 8;
    const short* gb0 = Bt + (size_t)(n0 + srow)      * DMODEL + schk * 8;
    const short* gb1 = Bt + (size_t)(n0 + 64 + srow) * DMODEL + schk * 8;
    const int lw = wv * 512;

    #define STAGE_G(buf, ko) do { \
        gload_lds16(ga0 + (ko), Asb + (buf) * 4096 + lw); \
        gload_lds16(ga1 + (ko), Asb + (buf) * 4096 + 2048 + lw); \
        gload_lds16(gb0 + (ko), Bsb + (buf) * 4096 + lw); \
        gload_lds16(gb1 + (ko), Bsb + (buf) * 4096 + 2048 + lw); \
    } while (0)

    STAGE_G(0, 0);
    STAGE_G(1, 32);

    const int rlo = (g ^ ((c16 >> 1) & 3)) << 3;
    for (int ks = 0; ks < 32; ++ks) {
        if (ks < 31) { VM_WAIT(4); } else { VM_WAIT(0); }
        barrier_sync();
        if (ks + 2 < 32) STAGE_G((ks + 2) % 3, (ks + 2) * 32);
        const int cur = ks % 3;
        s16x8 af[4], bfr[4];
        #pragma unroll
        for (int i = 0; i < 4; ++i)
            af[i] = *(const s16x8*)&Asb[cur * 4096 + (wm + i * 16 + c16) * 32 + rlo];
        #pragma unroll
        for (int j = 0; j < 4; ++j)
            bfr[j] = *(const s16x8*)&Bsb[cur * 4096 + (wn + j * 16 + c16) * 32 + rlo];
        #pragma unroll
        for (int i = 0; i < 4; ++i)
            #pragma unroll
            for (int j = 0; j < 4; ++j)
                acc[i][j] = MFMA_BF16(af[i], bfr[j], acc[i][j]);
    }
    #undef STAGE_G
}

// ---------------------------------------------------------------------------
// 128x64 GEMM mainloop for the output projection: BK=32, triple-buffered,
// 3 loads/step, vmcnt(3) ahead-2. 4 waves 2x2; per-wave 64x32 (acc[4][2]).
// ---------------------------------------------------------------------------
__device__ __forceinline__ void gemm_tile64(const short* __restrict__ A,
                                            const short* __restrict__ Bt,
                                            int m0, int n0, short* SM,
                                            f32x4 acc[4][2]) {
    const int tid  = threadIdx.x;
    const int lane = tid & 63;
    const int wv   = tid >> 6;
    const int wm   = (wv >> 1) * 64;
    const int wn   = (wv & 1) * 32;
    const int g = lane >> 4, c16 = lane & 15;

    short* Asb = SM;
    short* Bsb = SM + 12288;                      // 3 bufs x 2048

    const int srow = tid >> 2;                          // 0..63
    const int schk = (tid & 3) ^ ((tid >> 3) & 3);
    const short* ga0 = A  + (size_t)(m0 + srow)      * DMODEL + schk * 8;
    const short* ga1 = A  + (size_t)(m0 + 64 + srow) * DMODEL + schk * 8;
    const short* gb0 = Bt + (size_t)(n0 + srow)      * DMODEL + schk * 8;
    const int lw = wv * 512;

    #define SG64(buf, ko) do { \
        gload_lds16(ga0 + (ko), Asb + (buf) * 4096 + lw); \
        gload_lds16(ga1 + (ko), Asb + (buf) * 4096 + 2048 + lw); \
        gload_lds16(gb0 + (ko), Bsb + (buf) * 2048 + lw); \
    } while (0)

    SG64(0, 0);
    SG64(1, 32);

    const int rlo = (g ^ ((c16 >> 1) & 3)) << 3;
    for (int ks = 0; ks < 32; ++ks) {
        if (ks < 31) { VM_WAIT(3); } else { VM_WAIT(0); }
        barrier_sync();
        if (ks + 2 < 32) SG64((ks + 2) % 3, (ks + 2) * 32);
        const int cur = ks % 3;
        s16x8 af[4], bfr[2];
        #pragma unroll
        for (int i = 0; i < 4; ++i)
            af[i] = *(const s16x8*)&Asb[cur * 4096 + (wm + i * 16 + c16) * 32 + rlo];
        #pragma unroll
        for (int j = 0; j < 2; ++j)
            bfr[j] = *(const s16x8*)&Bsb[cur * 2048 + (wn + j * 16 + c16) * 32 + rlo];
        #pragma unroll
        for (int i = 0; i < 4; ++i)
            #pragma unroll
            for (int j = 0; j < 2; ++j)
                acc[i][j] = MFMA_BF16(af[i], bfr[j], acc[i][j]);
    }
    #undef SG64
}

// ---------------------------------------------------------------------------
// FUSED QKV GEMM (N=3072) + RoPE epilogue, coalesced LDS-repacked stores.
// grid (24,32) = 768 blocks = 3/CU. Balanced XCD remap (12tx x 8ty per XCD).
// ---------------------------------------------------------------------------
__global__ __launch_bounds__(256) void gemm_qkv(const short* __restrict__ xb,
                                                const short* __restrict__ wtb,
                                                short* __restrict__ Qo,
                                                short* __restrict__ Ko,
                                                short* __restrict__ Vt,
                                                const float* __restrict__ cosT,
                                                const float* __restrict__ sinT) {
    __shared__ __align__(16) short SM[24576];     // 48KB: staging, then repack

    const int dd    = blockIdx.x + 24 * blockIdx.y;  // xcd = dd%8
    const int xcd   = dd & 7;
    const int local = dd >> 3;                       // 0..95
    const int ty = (xcd & 3) * 8 + local / 12;       // 0..31
    const int tx = (xcd >> 2) * 12 + local % 12;     // 0..23
    const int m0 = ty * 128, n0 = tx * 128;
    const int z  = tx >> 3;                       // 0:Q 1:K 2:V (uniform/block)

    f32x4 acc[4][4] = {};
    gemm_tile(xb, wtb, m0, n0, SM, acc);

    const int tid  = threadIdx.x;
    const int lane = tid & 63;
    const int wv   = tid >> 6;
    const int wm   = (wv >> 1) * 64, wn = (wv & 1) * 64;
    const int g = lane >> 4, c16 = lane & 15;
    const int hbase = (n0 & 1023) >> 6;

    barrier_sync();                               // staging reads done -> reuse SM
    short (*RP)[136] = (short(*)[136])SM;         // 128 x 136 shorts

    if (z < 2) {
        short* outp = (z == 0) ? Qo : Ko;
        const float post = (z == 0) ? 0.18033688011112042f : 1.0f;  // 0.125*log2(e)
        #pragma unroll
        for (int j = 0; j < 4; ++j) {
            const int nl = wn + j * 16 + c16;
            const int d  = (n0 + nl) & 63;
            #pragma unroll
            for (int i = 0; i < 4; ++i) {
                #pragma unroll
                for (int r = 0; r < 4; ++r) {
                    const int ml = wm + i * 16 + g * 4 + r;
                    const int s  = (m0 + ml) & (S_LEN - 1);
                    float v = acc[i][j][r];
                    float vo = __shfl_xor(v, 1, 64);   // partner col = n^1
                    float cs = cosT[s * 32 + (d >> 1)];
                    float sn = sinT[s * 32 + (d >> 1)];
                    float res = (d & 1) ? (vo * sn + v * cs) : (v * cs - vo * sn);
                    RP[ml][nl] = f2bf(res * post);
                }
            }
        }
        barrier_sync();
        #pragma unroll
        for (int pass = 0; pass < 8; ++pass) {
            const int row = pass * 32 + (tid >> 3);   // 0..255
            const int k   = tid & 7;
            const int hh = row >> 7, ss = row & 127;
            const int m = m0 + ss;
            const int s = m & (S_LEN - 1), b = m >> 11;
            short* dst = outp + (((size_t)b * NH + hbase + hh) * S_LEN + s) * DH + k * 8;
            *(s16x8*)dst = *(const s16x8*)&RP[ss][hh * 64 + k * 8];
        }
    } else {
        #pragma unroll
        for (int j = 0; j < 4; ++j) {
            const int nl = wn + j * 16 + c16;
            #pragma unroll
            for (int i = 0; i < 4; ++i) {
                const int mlb = wm + i * 16 + g * 4;
                s16x4 pk;
                #pragma unroll
                for (int r = 0; r < 4; ++r) pk[r] = f2bf(acc[i][j][r]);
                *(s16x4*)&RP[nl][mlb] = pk;
            }
        }
        barrier_sync();
        const int b = m0 >> 11, sr0 = m0 & (S_LEN - 1);
        #pragma unroll
        for (int pass = 0; pass < 8; ++pass) {
            const int row = pass * 16 + (tid >> 4);   // 0..127 (h,d rows)
            const int k   = tid & 15;
            const int h = hbase + (row >> 6), d = row & 63;
            short* dst = Vt + (((size_t)b * NH + h) * DH + d) * S_LEN + sr0 + k * 8;
            *(s16x8*)dst = *(const s16x8*)&RP[row][k * 8];
        }
    }
}

// ---------------------------------------------------------------------------
// Causal flash attention. UN-MERGED blocks: grid (32 bh, 32 ci-index),
// ci = 31 - blockIdx.y (slow axis -> global longest-first dispatch, LPT
// balance at ~4 blocks/CU). Double-buffered K/V (T3-minimum: stage(t+1) ->
// compute(t) -> vmcnt(0) -> barrier). LDS 41KB -> 3 blocks/CU co-resident.
// bh on the fast axis: each XCD keeps 4 heads' K/V (2MB) in its L2.
// Swapped QK^T, lane-local softmax (unchanged core).
// ---------------------------------------------------------------------------
__global__ __launch_bounds__(256) void attn(const short* __restrict__ Q,
                                            const short* __restrict__ K,
                                            const short* __restrict__ Vt,
                                            short* __restrict__ O) {
    const int tid  = threadIdx.x;
    const int lane = tid & 63;
    const int w    = tid >> 6;
    const int g = lane >> 4, c16 = lane & 15;
    const int bh = blockIdx.x;                    // 0..31
    const int ci = 31 - blockIdx.y;               // longest-first
    const int ntiles = ci + 1;
    const int wq0 = ci * 64 + w * 16;
    const size_t base = (size_t)bh * S_LEN * DH;
    const short* Kb = K + base;
    const short* Vb = Vt + (size_t)bh * DH * S_LEN;
    const int b = bh >> 4, h = bh & 15;

    __shared__ __align__(16) short KL[2][4096];   // [64 kv][64 d] swizzled chunks
    __shared__ __align__(16) short VL[2][4096];   // [64 d][64 kv] swizzled chunks
    __shared__ __align__(16) short P2[4][16][72]; // per-wave P^T[q][kv]

    const int kr = tid >> 3;                      // 0..31
    const int kc = (tid & 7) ^ (kr & 7);
    const short* kg0 = Kb + (size_t)kr * DH + (kc << 3);
    const short* kg1 = Kb + (size_t)(32 + kr) * DH + (kc << 3);
    const short* vg0 = Vb + (size_t)kr * S_LEN + (kc << 3);
    const short* vg1 = Vb + (size_t)(32 + kr) * S_LEN + (kc << 3);
    const int lw = w * 512;                       // wave-uniform LDS base (shorts)
    const int kx = c16 & 7;

    // prologue: tile 0 -> buf0, Q frags, drain, sync
    gload_lds16(kg0, &KL[0][lw]);
    gload_lds16(kg1, &KL[0][2048 + lw]);
    gload_lds16(vg0, &VL[0][lw]);
    gload_lds16(vg1, &VL[0][2048 + lw]);
    s16x8 bq0 = *(const s16x8*)(Q + base + (size_t)(wq0 + c16) * DH + g * 8);
    s16x8 bq1 = *(const s16x8*)(Q + base + (size_t)(wq0 + c16) * DH + 32 + g * 8);
    VM_WAIT(0);
    barrier_sync();

    f32x4 o[4] = {};
    float lsum = 0.f;

    for (int tt = 0; tt < ntiles; ++tt) {
        const int cur = tt & 1;
        const bool more = (tt + 1 < ntiles);
        // stage next tile into the buffer everyone finished reading last iter
        if (more) {
            const size_t ko = (size_t)(tt + 1) * 64;
            gload_lds16(kg0 + ko * DH, &KL[cur ^ 1][lw]);
            gload_lds16(kg1 + ko * DH, &KL[cur ^ 1][2048 + lw]);
            gload_lds16(vg0 + ko,      &VL[cur ^ 1][lw]);
            gload_lds16(vg1 + ko,      &VL[cur ^ 1][2048 + lw]);
        }

        // QK^T swapped: A=K rows (kv), B=Q -> s[cg] = S^T[kv][q=c16]
        f32x4 s[4];
        __builtin_amdgcn_s_setprio(1);
        #pragma unroll
        for (int cg = 0; cg < 4; ++cg) {
            const int krow = (cg * 16 + c16) * 64;
            s16x8 kf0 = *(const s16x8*)&KL[cur][krow + ((g ^ kx) << 3)];
            s16x8 kf1 = *(const s16x8*)&KL[cur][krow + (((4 + g) ^ kx) << 3)];
            f32x4 zz = {};
            zz = MFMA_BF16(kf0, bq0, zz);
            s[cg] = MFMA_BF16(kf1, bq1, zz);
        }
        __builtin_amdgcn_s_setprio(0);

        s16x8 vf[4][2];
        #pragma unroll
        for (int nt = 0; nt < 4; ++nt) {
            const int vr = (nt * 16 + c16) * 64;
            vf[nt][0] = *(const s16x8*)&VL[cur][vr + ((g ^ kx) << 3)];
            vf[nt][1] = *(const s16x8*)&VL[cur][vr + (((4 + g) ^ kx) << 3)];
        }

        const bool diag = (tt == ci);
        const int qrel = w * 16 + c16;
        #pragma unroll
        for (int cg = 0; cg < 4; ++cg) {
            float e[4];
            #pragma unroll
            for (int r = 0; r < 4; ++r) {
                e[r] = exp2f(s[cg][r]);
                if (diag && (cg * 16 + g * 4 + r > qrel)) e[r] = 0.f;
            }
            lsum += (e[0] + e[1]) + (e[2] + e[3]);
            uint2 pk;
            pk.x = cvtpk_bf16(e[0], e[1]);
            pk.y = cvtpk_bf16(e[2], e[3]);
            *(uint2*)&P2[w][c16][cg * 16 + g * 4] = pk;   // ds_write_b64
        }
        asm volatile("s_waitcnt lgkmcnt(0)" ::: "memory");
        __builtin_amdgcn_sched_barrier(0);                // rule #18 fence
        s16x8 ap0 = *(const s16x8*)&P2[w][c16][g * 8];    // ds_read_b128
        s16x8 ap1 = *(const s16x8*)&P2[w][c16][32 + g * 8];

        __builtin_amdgcn_s_setprio(1);
        #pragma unroll
        for (int nt = 0; nt < 4; ++nt) {
            o[nt] = MFMA_BF16(ap0, vf[nt][0], o[nt]);
            o[nt] = MFMA_BF16(ap1, vf[nt][1], o[nt]);
        }
        __builtin_amdgcn_s_setprio(0);

        if (more) { VM_WAIT(0); }                 // next tile landed (mine)
        barrier_sync();                           // ... and everyone's
    }

    float lt = lsum;
    lt += __shfl_xor(lt, 16, 64);
    lt += __shfl_xor(lt, 32, 64);
    #pragma unroll
    for (int r = 0; r < 4; ++r) {
        const float linv = 1.0f / __shfl(lt, g * 4 + r, 64);
        #pragma unroll
        for (int nt = 0; nt < 4; ++nt) {
            O[((size_t)(b * S_LEN + wq0 + g * 4 + r)) * DMODEL
              + h * DH + nt * 16 + c16] = f2bf(o[nt][r] * linv);
        }
    }
}

// ---------------------------------------------------------------------------
// Output projection: C = Ob(bf16) @ wo, fp32 out. 128x64 tiles, grid (16,32)
// = 512 blocks = 2/CU. XCD remap: per XCD all 16 tx, 4 ty (B 2MB + A 1MB).
// ---------------------------------------------------------------------------
__global__ __launch_bounds__(256) void gemm_o(const short* __restrict__ Ob,
                                              const short* __restrict__ WoT,
                                              float* __restrict__ C) {
    __shared__ __align__(16) short SMl[18432];    // 36KB

    const int dd = blockIdx.x + 16 * blockIdx.y;  // 0..511, xcd = dd%8
    const int ti = (dd & 7) * 64 + (dd >> 3);     // bijective (512 = 8*64)
    const int tx = ti & 15, ty = ti >> 4;         // ty in [4*xcd, +4)
    const int m0 = ty * 128, n0 = tx * 64;

    f32x4 acc[4][2] = {};
    gemm_tile64(Ob, WoT, m0, n0, SMl, acc);

    const int tid  = threadIdx.x;
    const int lane = tid & 63;
    const int wv   = tid >> 6;
    const int wm   = (wv >> 1) * 64, wn = (wv & 1) * 32;
    const int g = lane >> 4, c16 = lane & 15;

    #pragma unroll
    for (int i = 0; i < 4; ++i)
        #pragma unroll
        for (int j = 0; j < 2; ++j) {
            const int n = n0 + wn + j * 16 + c16;
            #pragma unroll
            for (int r = 0; r < 4; ++r) {
                const int m = m0 + wm + i * 16 + g * 4 + r;
                C[(size_t)m * DMODEL + n] = acc[i][j][r];
            }
        }
}

// ---------------------------------------------------------------------------
extern "C" void kernel_launch(void* const* d_in, const int* in_sizes, int n_in,
                              void* d_out, int out_size, void* d_ws, size_t ws_size,
                              hipStream_t stream) {
    const float* x  = (const float*)d_in[0];
    const float* wq = (const float*)d_in[1];
    const float* wk = (const float*)d_in[2];
    const float* wv = (const float*)d_in[3];
    const float* wo = (const float*)d_in[4];
    float* out = (float*)d_out;

    char* ws = (char*)d_ws;
    short* wtb  = (short*)ws;                              // [4][1024][1024] bf16 (q,k,v,o)
    short* xb   = (short*)(ws + (8ull  << 20));            // [4096][1024] bf16
    float* cosT = (float*)(ws + (16ull << 20));            // [2048][32]
    float* sinT = (float*)(ws + (16ull << 20) + (256ull << 10));
    short* Qb   = (short*)(ws + (17ull << 20));            // [B*H][S][64] bf16 (pre-scaled)
    short* Kb   = (short*)(ws + (25ull << 20));            // [B*H][S][64] bf16
    short* Vtb  = (short*)(ws + (33ull << 20));            // [B*H][64][S] bf16 (transposed)
    short* Ob   = (short*)(ws + (41ull << 20));            // [4096][1024] bf16

    prep_all<<<dim3(16, 16, 5), 256, 0, stream>>>(wq, wk, wv, wo, x,
                                                  wtb, xb, cosT, sinT);

    gemm_qkv<<<dim3(24, 32), 256, 0, stream>>>(xb, wtb, Qb, Kb, Vtb, cosT, sinT);
    attn    <<<dim3(32, 32), 256, 0, stream>>>(Qb, Kb, Vtb, Ob);
    gemm_o  <<<dim3(16, 32), 256, 0, stream>>>(Ob, wtb + 3ull * DMODEL * DMODEL, out);
}